// Round 1
// baseline (35199.384 us; speedup 1.0000x reference)
//
#include <hip/hip_runtime.h>

// Problem constants: B=64, T=1024, I=512, H=1024, fp32 in/out.
#define B_  64
#define T_  1024
#define I_  512
#define H_  1024

typedef short short8 __attribute__((ext_vector_type(8)));
typedef float f32x4  __attribute__((ext_vector_type(4)));
typedef unsigned long long u64;

__device__ __forceinline__ unsigned short f2bf(float f) {
    unsigned int u = __float_as_uint(f);
    unsigned int r = u + 0x7fffu + ((u >> 16) & 1u);   // RNE
    return (unsigned short)(r >> 16);
}
__device__ __forceinline__ float bf2f(unsigned short s) {
    return __uint_as_float(((unsigned int)s) << 16);
}

// ---------------------------------------------------------------------------
// Kernel 1: xp = x @ input_w + b   ([65536,512] @ [512,1024] -> d_out)
// fp32 SGEMM, 128x128 tile, 256 threads, 8x8 per thread, BK=8. (unchanged)
// ---------------------------------------------------------------------------
#define BM 128
#define BN 128
#define BK 8

__global__ __launch_bounds__(256) void proj_kernel(
    const float* __restrict__ x, const float* __restrict__ w,
    const float* __restrict__ bias, float* __restrict__ out)
{
    __shared__ float As[BK][BM];
    __shared__ float Bs[BK][BN];

    const int tid = threadIdx.x;
    const int m0 = blockIdx.y * BM;
    const int n0 = blockIdx.x * BN;
    const int tx = tid & 15;
    const int ty = tid >> 4;

    const int arow = tid >> 1;
    const int acol = (tid & 1) * 4;
    const int brow = tid >> 5;
    const int bcol = (tid & 31) * 4;

    float acc[2][4][2][4];
    #pragma unroll
    for (int a = 0; a < 2; a++)
        #pragma unroll
        for (int b = 0; b < 4; b++)
            #pragma unroll
            for (int c = 0; c < 2; c++)
                #pragma unroll
                for (int d = 0; d < 4; d++) acc[a][b][c][d] = 0.f;

    for (int k0 = 0; k0 < I_; k0 += BK) {
        float4 av = *(const float4*)&x[(size_t)(m0 + arow) * I_ + k0 + acol];
        float4 bv = *(const float4*)&w[(size_t)(k0 + brow) * H_ + n0 + bcol];
        __syncthreads();
        As[acol + 0][arow] = av.x;
        As[acol + 1][arow] = av.y;
        As[acol + 2][arow] = av.z;
        As[acol + 3][arow] = av.w;
        *(float4*)&Bs[brow][bcol] = bv;
        __syncthreads();
        #pragma unroll
        for (int kk = 0; kk < BK; kk++) {
            float4 a0 = *(const float4*)&As[kk][ty * 4];
            float4 a1 = *(const float4*)&As[kk][64 + ty * 4];
            float4 b0 = *(const float4*)&Bs[kk][tx * 4];
            float4 b1 = *(const float4*)&Bs[kk][64 + tx * 4];
            const float am[2][4] = {{a0.x,a0.y,a0.z,a0.w},{a1.x,a1.y,a1.z,a1.w}};
            const float bn[2][4] = {{b0.x,b0.y,b0.z,b0.w},{b1.x,b1.y,b1.z,b1.w}};
            #pragma unroll
            for (int mb = 0; mb < 2; mb++)
                #pragma unroll
                for (int mr = 0; mr < 4; mr++)
                    #pragma unroll
                    for (int nb = 0; nb < 2; nb++)
                        #pragma unroll
                        for (int nr = 0; nr < 4; nr++)
                            acc[mb][mr][nb][nr] += am[mb][mr] * bn[nb][nr];
        }
    }

    float4 bias0 = *(const float4*)&bias[n0 + tx * 4];
    float4 bias1 = *(const float4*)&bias[n0 + 64 + tx * 4];
    const float bb[2][4] = {{bias0.x,bias0.y,bias0.z,bias0.w},
                            {bias1.x,bias1.y,bias1.z,bias1.w}};
    #pragma unroll
    for (int mb = 0; mb < 2; mb++)
        #pragma unroll
        for (int mr = 0; mr < 4; mr++) {
            int m = m0 + mb * 64 + ty * 4 + mr;
            #pragma unroll
            for (int nb = 0; nb < 2; nb++) {
                float4 v;
                v.x = acc[mb][mr][nb][0] + bb[nb][0];
                v.y = acc[mb][mr][nb][1] + bb[nb][1];
                v.z = acc[mb][mr][nb][2] + bb[nb][2];
                v.w = acc[mb][mr][nb][3] + bb[nb][3];
                *(float4*)&out[(size_t)m * H_ + n0 + nb * 64 + tx * 4] = v;
            }
        }
}

// ---------------------------------------------------------------------------
// Kernel 2: sequential scan, TAG-IN-DATA message passing (no flags, no
// fences, no per-step barriers).
//
// Each h element is published as one naturally-atomic 8B word:
//     { tag32 = t+1  |  bf16_hi<<16 | bf16_lo }
// Consumers validate freshness per-value from the tag that arrived WITH the
// payload, so the entire ordering machinery of the previous version
// (vmcnt drain -> flag store -> flag poll -> acquire fence) disappears from
// the critical path. The tag-check retry loop IS the poll, merged into the
// depth-PFD pipelined loads. Waves free-run: batches are independent, so
// wave w of all wgs forms a closed 16-batch plane; data deps bound skew to
// 1 step, which makes the 2-parity buffer overwrite-safe (the producer of
// tag t+2 has, by dependency, consumed all tag-(t+1) data, which implies
// every wave already consumed tag-t).
//
// W slice now lives fully in LDS (hi + lo bf16 fragments, 64 KB) to free the
// 128 VGPRs previously pinned by wh[], making room for the 128-VGPR tagged
// prefetch buffer (PFD=8 chunks x 8 u64).
//
// MFMA 16x16x32_bf16: A: m=lane&15,k=quad*8+i  B: n=lane&15,k=quad*8+i
//                     C/D: col=lane&15, row=quad*4+reg  (HW-verified earlier)
// ---------------------------------------------------------------------------
#define PFD 8   // prefetch depth in 32-k chunks; 8*8 = 64 u64 loads in flight

__global__ __launch_bounds__(256, 1) void scan_kernel(
    const float* __restrict__ W,        // hidden_w [H][H]
    float* __restrict__ out,            // d_out: xp on entry, h on exit
    u64* __restrict__ hbuf)             // ws: [2 parity][64 b][1024 k] tagged
{
    __shared__ short8 whds[32][64];     // hi-part B-fragments, 32 KB
    __shared__ short8 wlds[32][64];     // lo-part B-fragments, 32 KB

    const int wg   = blockIdx.x;        // 0..63 -> columns [wg*16, wg*16+16)
    const int tid  = threadIdx.x;
    const int wave = tid >> 6;          // 0..3 -> rows [wave*16, wave*16+16)
    const int lane = tid & 63;
    const int quad = lane >> 4;
    const int l16  = lane & 15;
    const int jbase = wg * 16;
    const int b0    = wave * 16;
    const int j     = jbase + l16;
    const int row   = b0 + l16;         // A-fragment row for this lane

    // ---- preload W slice into LDS: each wave fills its 8 kc chunks ----
    #pragma unroll
    for (int kc = 0; kc < 32; kc++) {
        if ((kc >> 3) == wave) {
            short8 whv, wlv;
            #pragma unroll
            for (int i = 0; i < 8; i++) {
                float wv = W[(size_t)(kc * 32 + quad * 8 + i) * H_ + j];
                unsigned short hi = f2bf(wv);
                whv[i] = (short)hi;
                wlv[i] = (short)f2bf(wv - bf2f(hi));
            }
            whds[kc][lane] = whv;
            wlds[kc][lane] = wlv;
        }
    }
    __syncthreads();   // the ONLY barrier in this kernel

    const size_t TH = (size_t)T_ * H_;
    size_t oidx[4];
    float xv[4];
    #pragma unroll
    for (int r = 0; r < 4; r++) {
        int b = b0 + quad * 4 + r;
        oidx[r] = (size_t)b * TH + j;      // (b, t=0, j)
        xv[r] = out[oidx[r]];
    }

    // per-lane u64 base (without parity / kc): row*1024 + quad*8
    const int rbase = row * 1024 + quad * 8;

    for (int t = 0; t < T_; t++) {
        // prefetch next step's xp early (plain cached loads, wg-private data)
        float nxv[4] = {0.f, 0.f, 0.f, 0.f};
        if (t + 1 < T_) {
            #pragma unroll
            for (int r = 0; r < 4; r++) nxv[r] = out[oidx[r] + H_];
        }

        f32x4 acc = {0.f, 0.f, 0.f, 0.f};
        if (t > 0) {
            const u64* hb = hbuf + (size_t)((t - 1) & 1) * 65536 + rbase;
            const unsigned int want = (unsigned int)t;   // tag of h_{t-1}

            // depth-PFD pipelined tagged loads; issue speculatively, no wait
            u64 buf[PFD][8];
            #pragma unroll
            for (int d = 0; d < PFD; d++)
                #pragma unroll
                for (int i = 0; i < 8; i++)
                    buf[d][i] = __hip_atomic_load(hb + d * 32 + i,
                        __ATOMIC_RELAXED, __HIP_MEMORY_SCOPE_AGENT);

            #pragma unroll
            for (int kc = 0; kc < 32; kc++) {
                const int slot = kc & (PFD - 1);
                u64 c[8];
                #pragma unroll
                for (int i = 0; i < 8; i++) c[i] = buf[slot][i];
                if (kc + PFD < 32) {
                    #pragma unroll
                    for (int i = 0; i < 8; i++)
                        buf[slot][i] = __hip_atomic_load(
                            hb + (kc + PFD) * 32 + i,
                            __ATOMIC_RELAXED, __HIP_MEMORY_SCOPE_AGENT);
                }
                // validate tags; retry (rare in steady state) until fresh
                bool ok = true;
                #pragma unroll
                for (int i = 0; i < 8; i++)
                    ok = ok && ((unsigned int)(c[i] >> 32) == want);
                while (!ok) {
                    #pragma unroll
                    for (int i = 0; i < 8; i++)
                        c[i] = __hip_atomic_load(hb + kc * 32 + i,
                            __ATOMIC_RELAXED, __HIP_MEMORY_SCOPE_AGENT);
                    ok = true;
                    #pragma unroll
                    for (int i = 0; i < 8; i++)
                        ok = ok && ((unsigned int)(c[i] >> 32) == want);
                }

                short8 ah, al;
                #pragma unroll
                for (int i = 0; i < 8; i++) {
                    unsigned int d = (unsigned int)c[i];
                    ah[i] = (short)(d >> 16);
                    al[i] = (short)(d & 0xffffu);
                }
                short8 whv = whds[kc][lane];
                short8 wlv = wlds[kc][lane];
                acc = __builtin_amdgcn_mfma_f32_16x16x32_bf16(ah, whv, acc, 0, 0, 0);
                acc = __builtin_amdgcn_mfma_f32_16x16x32_bf16(ah, wlv, acc, 0, 0, 0);
                acc = __builtin_amdgcn_mfma_f32_16x16x32_bf16(al, whv, acc, 0, 0, 0);
            }
        }

        // epilogue: h = tanh(acc + xp); publish tagged words, fire-and-forget
        float hv[4];
        u64* ob = hbuf + (size_t)(t & 1) * 65536;
        const u64 tagw = ((u64)(unsigned int)(t + 1)) << 32;
        #pragma unroll
        for (int r = 0; r < 4; r++) {
            int b = b0 + quad * 4 + r;
            hv[r] = tanhf(acc[r] + xv[r]);
            if (t + 1 < T_) {
                unsigned short hi = f2bf(hv[r]);
                unsigned short lo = f2bf(hv[r] - bf2f(hi));
                u64 pk = tagw |
                    (u64)(((unsigned int)hi << 16) | (unsigned int)lo);
                __hip_atomic_store(&ob[(size_t)b * 1024 + j], pk,
                                   __ATOMIC_RELAXED, __HIP_MEMORY_SCOPE_AGENT);
            }
        }

        // off critical path: fp32 h store to d_out (wg-private addresses)
        #pragma unroll
        for (int r = 0; r < 4; r++) {
            out[oidx[r]] = hv[r];
            oidx[r] += H_;
            xv[r] = nxv[r];
        }
    }
}

// ---------------------------------------------------------------------------
extern "C" void kernel_launch(void* const* d_in, const int* in_sizes, int n_in,
                              void* d_out, int out_size, void* d_ws, size_t ws_size,
                              hipStream_t stream) {
    const float* x        = (const float*)d_in[0];  // [B,T,I]
    const float* hidden_w = (const float*)d_in[1];  // [H,H]
    const float* input_w  = (const float*)d_in[2];  // [I,H]
    const float* bias     = (const float*)d_in[3];  // [H]
    float* out = (float*)d_out;                     // [B,T,H]

    // ws layout: hbuf = 2 parity x 64 x 1024 tagged u64 = 1 MiB.
    // Zeroing kills stale tags from previous launches (tag 0 never matches).
    u64* hbuf = (u64*)d_ws;
    hipMemsetAsync(d_ws, 0, (size_t)2 * 65536 * sizeof(u64), stream);

    dim3 pgrid(H_ / BN, (B_ * T_) / BM);   // (8, 512)
    proj_kernel<<<pgrid, 256, 0, stream>>>(x, input_w, bias, out);
    scan_kernel<<<64, 256, 0, stream>>>(hidden_w, out, hbuf);
}

// Round 2
// 8276.496 us; speedup vs baseline: 4.2529x; 4.2529x over previous
//
#include <hip/hip_runtime.h>

// Problem constants: B=64, T=1024, I=512, H=1024, fp32 in/out.
#define B_  64
#define T_  1024
#define I_  512
#define H_  1024

typedef short short8 __attribute__((ext_vector_type(8)));
typedef float f32x4  __attribute__((ext_vector_type(4)));
typedef unsigned int u32x4 __attribute__((ext_vector_type(4)));
typedef unsigned long long u64;

__device__ __forceinline__ unsigned short f2bf(float f) {
    unsigned int u = __float_as_uint(f);
    unsigned int r = u + 0x7fffu + ((u >> 16) & 1u);   // RNE
    return (unsigned short)(r >> 16);
}
__device__ __forceinline__ float bf2f(unsigned short s) {
    return __uint_as_float(((unsigned int)s) << 16);
}

// Agent-scope cache-bypassing 16B load (coherent at MALL, like the compiler's
// agent-scope atomic loads, but 2x wider than the 8B atomic max). Atomicity is
// NOT needed: the flag protocol guarantees data is fully published before read.
__device__ __forceinline__ u32x4 load_b128_agent(const void* p) {
    u32x4 r;
    asm volatile("global_load_dwordx4 %0, %1, off sc1"
                 : "=v"(r) : "v"(p) : "memory");
    return r;
}

// ---------------------------------------------------------------------------
// Kernel 1: xp = x @ input_w + b   ([65536,512] @ [512,1024] -> d_out)
// fp32 SGEMM, 128x128 tile, 256 threads, 8x8 per thread, BK=8. (unchanged)
// ---------------------------------------------------------------------------
#define BM 128
#define BN 128
#define BK 8

__global__ __launch_bounds__(256) void proj_kernel(
    const float* __restrict__ x, const float* __restrict__ w,
    const float* __restrict__ bias, float* __restrict__ out)
{
    __shared__ float As[BK][BM];
    __shared__ float Bs[BK][BN];

    const int tid = threadIdx.x;
    const int m0 = blockIdx.y * BM;
    const int n0 = blockIdx.x * BN;
    const int tx = tid & 15;
    const int ty = tid >> 4;

    const int arow = tid >> 1;
    const int acol = (tid & 1) * 4;
    const int brow = tid >> 5;
    const int bcol = (tid & 31) * 4;

    float acc[2][4][2][4];
    #pragma unroll
    for (int a = 0; a < 2; a++)
        #pragma unroll
        for (int b = 0; b < 4; b++)
            #pragma unroll
            for (int c = 0; c < 2; c++)
                #pragma unroll
                for (int d = 0; d < 4; d++) acc[a][b][c][d] = 0.f;

    for (int k0 = 0; k0 < I_; k0 += BK) {
        float4 av = *(const float4*)&x[(size_t)(m0 + arow) * I_ + k0 + acol];
        float4 bv = *(const float4*)&w[(size_t)(k0 + brow) * H_ + n0 + bcol];
        __syncthreads();
        As[acol + 0][arow] = av.x;
        As[acol + 1][arow] = av.y;
        As[acol + 2][arow] = av.z;
        As[acol + 3][arow] = av.w;
        *(float4*)&Bs[brow][bcol] = bv;
        __syncthreads();
        #pragma unroll
        for (int kk = 0; kk < BK; kk++) {
            float4 a0 = *(const float4*)&As[kk][ty * 4];
            float4 a1 = *(const float4*)&As[kk][64 + ty * 4];
            float4 b0 = *(const float4*)&Bs[kk][tx * 4];
            float4 b1 = *(const float4*)&Bs[kk][64 + tx * 4];
            const float am[2][4] = {{a0.x,a0.y,a0.z,a0.w},{a1.x,a1.y,a1.z,a1.w}};
            const float bn[2][4] = {{b0.x,b0.y,b0.z,b0.w},{b1.x,b1.y,b1.z,b1.w}};
            #pragma unroll
            for (int mb = 0; mb < 2; mb++)
                #pragma unroll
                for (int mr = 0; mr < 4; mr++)
                    #pragma unroll
                    for (int nb = 0; nb < 2; nb++)
                        #pragma unroll
                        for (int nr = 0; nr < 4; nr++)
                            acc[mb][mr][nb][nr] += am[mb][mr] * bn[nb][nr];
        }
    }

    float4 bias0 = *(const float4*)&bias[n0 + tx * 4];
    float4 bias1 = *(const float4*)&bias[n0 + 64 + tx * 4];
    const float bb[2][4] = {{bias0.x,bias0.y,bias0.z,bias0.w},
                            {bias1.x,bias1.y,bias1.z,bias1.w}};
    #pragma unroll
    for (int mb = 0; mb < 2; mb++)
        #pragma unroll
        for (int mr = 0; mr < 4; mr++) {
            int m = m0 + mb * 64 + ty * 4 + mr;
            #pragma unroll
            for (int nb = 0; nb < 2; nb++) {
                float4 v;
                v.x = acc[mb][mr][nb][0] + bb[nb][0];
                v.y = acc[mb][mr][nb][1] + bb[nb][1];
                v.z = acc[mb][mr][nb][2] + bb[nb][2];
                v.w = acc[mb][mr][nb][3] + bb[nb][3];
                *(float4*)&out[(size_t)m * H_ + n0 + nb * 64 + tx * 4] = v;
            }
        }
}

// ---------------------------------------------------------------------------
// Kernel 2: sequential scan, per-wave flag protocol + SWIZZLED h exchange.
//
// Protocol (proven flag design, refined): producer wave p of wg publishes its
// 16 columns x 16 batches of h_t, drains vmcnt(0) (stores at MALL coherence
// point), then lane0 sets flags[p][wg] = t+1. Consumer wave (plane p) polls
// flags[p][0..63] (one per lane, __all). No __syncthreads in the loop: the 4
// batch-planes are independent chains and decouple fully.
//
// h exchange layout (the round-2 change): hbuf is swizzled into the A-fragment
// consumption order so each consumer lane's 8 packed u32 for a k-chunk are two
// 16B-contiguous blocks with lanes adjacent (4 lanes/cacheline):
//   u32 idx = ((par*4 + plane)*32 + kc)*512 + half*256 + lane*4 + i4
// where lane = quad*16 + (b&15), k = kc*32 + quad*8 + half*4 + i4.
// Loads are 2x global_load_dwordx4 sc1 per chunk (inline asm, agent scope):
// 32 cacheline requests/chunk/wave instead of 128, 2 instrs instead of 4.
// Manual PFD=8 pipelining with counted s_waitcnt vmcnt(14) (safe vs foreign
// vmem ops: vmcnt retires in issue order, so extra younger ops only make the
// wait more conservative) + sched_barrier(0) so hipcc can't hoist the unpack
// above the wait (guide rule #18).
//
// MFMA 16x16x32_bf16: A: m=lane&15,k=quad*8+i  B: n=lane&15,k=quad*8+i
//                     C/D: col=lane&15, row=quad*4+reg  (HW-verified earlier)
// 3 independent accumulators break the 96-deep dependent MFMA chain.
// ---------------------------------------------------------------------------
#define PFD 8   // prefetch depth in 32-k chunks; 8*2 = 16 dwordx4 in flight

__global__ __launch_bounds__(256, 1) void scan_kernel(
    const float* __restrict__ W,        // hidden_w [H][H]
    float* __restrict__ out,            // d_out: xp on entry, h on exit
    unsigned int* __restrict__ hbuf,    // ws: swizzled [2][4][32][2][64][4] u32
    int* __restrict__ flags)            // ws: [4 plane][64 wg] ints, pre-zeroed
{
    __shared__ short8 wlds[32][64];     // lo-part B-fragments, 32 KB

    const int wg   = blockIdx.x;        // 0..63 -> columns [wg*16, wg*16+16)
    const int tid  = threadIdx.x;
    const int wave = tid >> 6;          // plane: batches [wave*16, wave*16+16)
    const int lane = tid & 63;
    const int quad = lane >> 4;
    const int l16  = lane & 15;
    const int jbase = wg * 16;
    const int b0    = wave * 16;
    const int j     = jbase + l16;

    // ---- preload W slice: wh -> regs (all kc), wl -> LDS (my 8 kc) ----
    short8 wh[32];
    #pragma unroll
    for (int kc = 0; kc < 32; kc++) {
        short8 wlv;
        #pragma unroll
        for (int i = 0; i < 8; i++) {
            float wv = W[(size_t)(kc * 32 + quad * 8 + i) * H_ + j];
            unsigned short hi = f2bf(wv);
            wh[kc][i] = (short)hi;
            wlv[i] = (short)f2bf(wv - bf2f(hi));
        }
        if ((kc >> 3) == wave) wlds[kc][lane] = wlv;
    }
    __syncthreads();    // only for the W-LDS fill; none in the t-loop

    const size_t TH = (size_t)T_ * H_;
    size_t oidx[4];
    float xv[4];
    #pragma unroll
    for (int r = 0; r < 4; r++) {
        int b = b0 + quad * 4 + r;
        oidx[r] = (size_t)b * TH + j;      // (b, t=0, j)
        xv[r] = out[oidx[r]];
    }

    // consumer: byte base of my (plane, lane) within parity-0 region
    const char* hb_base = (const char*)hbuf + (size_t)wave * 65536
                        + (size_t)lane * 16;
    // producer: u32 base (parity-0) for my (j, quad) slot; element r at +r*4
    const int pbase = ((j >> 5) << 9) + (((j >> 2) & 1) << 8)
                    + ((j >> 3) & 3) * 64 + quad * 16 + (j & 3);
    unsigned int* pb_base = hbuf + (size_t)wave * 16384 + pbase;

    int* flagp = flags + wave * 64;      // my plane's flags; I publish [wg]

    for (int t = 0; t < T_; t++) {
        // prefetch next step's xp early (plain cached loads, wg-private data)
        float nxv[4] = {0.f, 0.f, 0.f, 0.f};
        if (t + 1 < T_) {
            #pragma unroll
            for (int r = 0; r < 4; r++) nxv[r] = out[oidx[r] + H_];
        }

        f32x4 a0 = {0.f,0.f,0.f,0.f}, a1 = {0.f,0.f,0.f,0.f},
              a2 = {0.f,0.f,0.f,0.f};
        if (t > 0) {
            // wait until every wg's plane-`wave` producer published h_{t-1}
            while (true) {
                int v = __hip_atomic_load(&flagp[lane], __ATOMIC_RELAXED,
                                          __HIP_MEMORY_SCOPE_AGENT);
                if (__all(v >= t)) break;
            }
            __builtin_amdgcn_fence(__ATOMIC_ACQUIRE, "workgroup");

            const char* hb = hb_base + (size_t)((t - 1) & 1) * 262144;

            u32x4 buf[PFD][2];
            #pragma unroll
            for (int d = 0; d < PFD; d++) {
                buf[d][0] = load_b128_agent(hb + d * 2048);
                buf[d][1] = load_b128_agent(hb + d * 2048 + 1024);
            }

            #pragma unroll
            for (int kc = 0; kc < 32; kc++) {
                if (kc < 24) {
                    asm volatile("s_waitcnt vmcnt(14)" ::: "memory");
                } else if (kc == 24) {
                    asm volatile("s_waitcnt vmcnt(0)" ::: "memory");
                }
                __builtin_amdgcn_sched_barrier(0);

                u32x4 c0 = buf[kc & (PFD - 1)][0];
                u32x4 c1 = buf[kc & (PFD - 1)][1];
                short8 ah, al;
                #pragma unroll
                for (int i = 0; i < 4; i++) {
                    ah[i]     = (short)(c0[i] >> 16);
                    al[i]     = (short)(c0[i] & 0xffffu);
                    ah[4 + i] = (short)(c1[i] >> 16);
                    al[4 + i] = (short)(c1[i] & 0xffffu);
                }
                short8 wlv = wlds[kc][lane];
                a0 = __builtin_amdgcn_mfma_f32_16x16x32_bf16(ah, wh[kc], a0, 0, 0, 0);
                a1 = __builtin_amdgcn_mfma_f32_16x16x32_bf16(ah, wlv,    a1, 0, 0, 0);
                a2 = __builtin_amdgcn_mfma_f32_16x16x32_bf16(al, wh[kc], a2, 0, 0, 0);

                if (kc + PFD < 32) {
                    buf[kc & (PFD - 1)][0] =
                        load_b128_agent(hb + (kc + PFD) * 2048);
                    buf[kc & (PFD - 1)][1] =
                        load_b128_agent(hb + (kc + PFD) * 2048 + 1024);
                }
            }
        }

        // epilogue: h = tanh(acc + xp); publish swizzled u32s, then flag
        float hv[4];
        #pragma unroll
        for (int r = 0; r < 4; r++)
            hv[r] = tanhf(a0[r] + a1[r] + a2[r] + xv[r]);

        if (t + 1 < T_) {
            unsigned int* pb = pb_base + (size_t)(t & 1) * 65536;
            #pragma unroll
            for (int r = 0; r < 4; r++) {
                unsigned short hi = f2bf(hv[r]);
                unsigned short lo = f2bf(hv[r] - bf2f(hi));
                unsigned int pk = ((unsigned int)hi << 16) | (unsigned int)lo;
                __hip_atomic_store(&pb[r * 4], pk, __ATOMIC_RELAXED,
                                   __HIP_MEMORY_SCOPE_AGENT);
            }
            asm volatile("s_waitcnt vmcnt(0)" ::: "memory");
            if (lane == 0)
                __hip_atomic_store(&flagp[wg], t + 1, __ATOMIC_RELAXED,
                                   __HIP_MEMORY_SCOPE_AGENT);
        }

        // off critical path: fp32 h store to d_out (wg-private addresses)
        #pragma unroll
        for (int r = 0; r < 4; r++) {
            out[oidx[r]] = hv[r];
            oidx[r] += H_;
            xv[r] = nxv[r];
        }
    }
}

// ---------------------------------------------------------------------------
extern "C" void kernel_launch(void* const* d_in, const int* in_sizes, int n_in,
                              void* d_out, int out_size, void* d_ws, size_t ws_size,
                              hipStream_t stream) {
    const float* x        = (const float*)d_in[0];  // [B,T,I]
    const float* hidden_w = (const float*)d_in[1];  // [H,H]
    const float* input_w  = (const float*)d_in[2];  // [I,H]
    const float* bias     = (const float*)d_in[3];  // [H]
    float* out = (float*)d_out;                     // [B,T,H]

    // ws layout: hbuf swizzled [2][4][32][2][64][4] u32 = 512 KiB, then flags
    unsigned int* hbuf = (unsigned int*)d_ws;
    int* flags = (int*)((char*)d_ws + (size_t)512 * 1024);

    hipMemsetAsync(flags, 0, 4 * 64 * sizeof(int), stream);

    dim3 pgrid(H_ / BN, (B_ * T_) / BM);   // (8, 512)
    proj_kernel<<<pgrid, 256, 0, stream>>>(x, input_w, bias, out);
    scan_kernel<<<64, 256, 0, stream>>>(hidden_w, out, hbuf, flags);
}